// Round 8
// baseline (26.581 us; speedup 1.0000x reference)
//
#include <hip/hip_runtime.h>
#include <hip/hip_bf16.h>

// Volterra conv (K=3, orders 1+2) as ONE fused bf16 MFMA GEMM kernel (no prep pass):
// out[b, l, o] = sum_{c,f} A[l, c*64+f] * Wc[c*64+f, o]
//   f<9: linear xp[f]; 9<=f<54: xp[P]*xp[Q]/sqrt(45); f>=54: 0-pad
// Scale 1/sqrt(45) is folded into the A side (xq[j] = xp[j]*S; pr = xq[P]*xp[Q]),
// so B-side uses RAW W1/W2 values, loaded register-direct in MFMA B-frag order:
//   lane (kh=lane>>5, col=lane&31); frag(ks,nb) slot e -> f = ks*16+kh*8+e,
//   W row = (c*9+f) in W1 if f<9, (c*81+P*9+Q) in W2 if f<54, else zero;
//   column = nb*32+col.  Compile-time rows via template<KH> + unrolled ks/j/h.
// Flat out = b*262144 + h_pix*4096 + w_pix*64 + o; bias = bias_w[h_pix] (zeros).
// Structure otherwise = r4 (best known): grid 256=(b,h), 512 thr = 8 waves,
// K-split 8 ch/wave, full unroll, permlane half-exchange, LDS only for the
// final 8-way cross-wave K reduction.

typedef __bf16 bf16x8 __attribute__((ext_vector_type(8)));
typedef float f32x16 __attribute__((ext_vector_type(16)));

#define SCALE_Q 0.14907119849998599f  // 1/sqrt(45)

constexpr int cP[45] = {
  0,0,0,0,0,0,0,0,0, 1,1,1,1,1,1,1,1, 2,2,2,2,2,2,2,
  3,3,3,3,3,3, 4,4,4,4,4, 5,5,5,5, 6,6,6, 7,7, 8};
constexpr int cQ[45] = {
  0,1,2,3,4,5,6,7,8, 1,2,3,4,5,6,7,8, 2,3,4,5,6,7,8,
  3,4,5,6,7,8, 4,5,6,7,8, 5,6,7,8, 6,7,8, 7,8, 8};

union AFrag { unsigned int u[4]; bf16x8 v; };
union BFrag { unsigned int u[4]; bf16x8 v; };

__device__ inline unsigned int pack_bf16x2(float a, float b){
  union { __hip_bfloat16 h; unsigned short s; } ca, cb;
  ca.h = __float2bfloat16(a);
  cb.h = __float2bfloat16(b);
  return (unsigned int)ca.s | ((unsigned int)cb.s << 16);
}

// half-exchange: U = own k-low dword, V = own k-high dword ->
// o0 = frag word for output rows 0..31, o1 = for rows 32..63.
__device__ inline void half_swap(unsigned int U, unsigned int V,
                                 unsigned int& o0, unsigned int& o1, int lane){
#if __has_builtin(__builtin_amdgcn_permlane32_swap)
  auto rr = __builtin_amdgcn_permlane32_swap(U, V, false, false);
  o0 = rr[0]; o1 = rr[1];
#else
  unsigned int Ux = (unsigned int)__shfl_xor((int)U, 32);
  unsigned int Vx = (unsigned int)__shfl_xor((int)V, 32);
  const bool hi = (lane >= 32);
  o0 = hi ? Vx : U;
  o1 = hi ? V : Ux;
#endif
}

// raw-W loads for this lane's k-half KH into rw[ks*16 + j*4 + {v(f0),v(f1),v+32(f0),v+32(f1)}]
// (all F, rows, and membership W1/W2 are compile-time after unroll)
template<int KH>
__device__ inline void loadW(const float* __restrict__ W1, const float* __restrict__ W2,
                             int c, int col, float (&rw)[64]){
  #pragma unroll
  for (int ks = 0; ks < 4; ++ks){
    #pragma unroll
    for (int j = 0; j < 4; ++j){
      #pragma unroll
      for (int h = 0; h < 2; ++h){
        const int F = ks * 16 + KH * 8 + 2 * j + h;   // constant after unroll
        float v0, v1;
        if (F < 9){
          v0 = W1[(c * 9 + F) * 64 + col];
          v1 = W1[(c * 9 + F) * 64 + col + 32];
        } else if (F < 54){
          const int row = c * 81 + cP[F - 9] * 9 + cQ[F - 9];
          v0 = W2[row * 64 + col];
          v1 = W2[row * 64 + col + 32];
        } else { v0 = 0.0f; v1 = 0.0f; }
        rw[ks * 16 + j * 4 + h]     = v0;
        rw[ks * 16 + j * 4 + 2 + h] = v1;
      }
    }
  }
}

// ---------------- single fused kernel ----------------
__global__ __launch_bounds__(512, 2) void volt_main(const float* __restrict__ x,
                                                    const float* __restrict__ W1,
                                                    const float* __restrict__ W2,
                                                    const float* __restrict__ bias_w,
                                                    float* __restrict__ out){
  __shared__ float red[8 * 4096];              // 128 KB: per-wave partial 64x64 tiles
  const int tid  = threadIdx.x;
  const int lane = tid & 63;
  const int kv   = tid >> 6;                   // wave 0..7, channels kv*8..kv*8+7
  const int b    = blockIdx.x >> 6;
  const int h0   = blockIdx.x & 63;

  const int kh   = lane >> 5;
  const int colb = lane & 31;

  const int hm = (h0 > 0)  ? h0 - 1 : 0;       // clamped; masked in build
  const int hp = (h0 < 63) ? h0 + 1 : 63;
  const float* xw = x + ((size_t)(b * 64 + kv * 8)) * 4096;

  f32x16 acc00{}, acc01{}, acc10{}, acc11{};   // [row-half][col-half]

  #pragma unroll
  for (int i = 0; i < 8; ++i){
    const int c = kv * 8 + i;

    // ---- B fragments register-direct from raw weights (kh-divergent loads) ----
    float rw[64];
    if (kh == 0) loadW<0>(W1, W2, c, colb, rw);
    else         loadW<1>(W1, W2, c, colb, rw);

    // ---- x rows for this channel ----
    const float* xc = xw + (size_t)i * 4096;
    float cx0 = xc[hm * 64 + lane];
    float cx1 = xc[h0 * 64 + lane];
    float cx2 = xc[hp * 64 + lane];

    // ---- features for this lane's pixel (w = lane) ----
    float xp[9];
    {
      float rows[3] = {cx0, cx1, cx2};
      #pragma unroll
      for (int dh = 0; dh < 3; ++dh){
        float mid = rows[dh];
        if (dh == 0 && h0 == 0)  mid = 0.f;    // wave-uniform row clamp
        if (dh == 2 && h0 == 63) mid = 0.f;
        float lf = __shfl(mid, lane - 1);
        float rt = __shfl(mid, lane + 1);
        xp[dh * 3 + 0] = (lane == 0)  ? 0.f : lf;
        xp[dh * 3 + 1] = mid;
        xp[dh * 3 + 2] = (lane == 63) ? 0.f : rt;
      }
    }
    float xq[9];
    #pragma unroll
    for (int j = 0; j < 9; ++j) xq[j] = xp[j] * SCALE_Q;   // scale fold (A side)

    unsigned int d[32];                        // 64 bf16 feature slots as dwords
    #pragma unroll
    for (int s = 0; s < 32; ++s){
      const int f0 = 2 * s, f1 = 2 * s + 1;    // constants after unroll
      float a  = (f0 < 9) ? xp[f0] : ((f0 < 54) ? xq[cP[f0-9]] * xp[cQ[f0-9]] : 0.0f);
      float b2 = (f1 < 9) ? xp[f1] : ((f1 < 54) ? xq[cP[f1-9]] * xp[cQ[f1-9]] : 0.0f);
      d[s] = pack_bf16x2(a, b2);
    }

    // ---- pack B fragments ----
    BFrag Bf[8];
    #pragma unroll
    for (int ks = 0; ks < 4; ++ks){
      #pragma unroll
      for (int j = 0; j < 4; ++j){
        Bf[ks*2+0].u[j] = pack_bf16x2(rw[ks*16 + j*4 + 0], rw[ks*16 + j*4 + 1]);
        Bf[ks*2+1].u[j] = pack_bf16x2(rw[ks*16 + j*4 + 2], rw[ks*16 + j*4 + 3]);
      }
    }

    // ---- A-frag half-exchange ----
    AFrag a0[4], a1[4];
    #pragma unroll
    for (int ks = 0; ks < 4; ++ks){
      #pragma unroll
      for (int j = 0; j < 4; ++j){
        half_swap(d[ks * 8 + j], d[ks * 8 + 4 + j], a0[ks].u[j], a1[ks].u[j], lane);
      }
    }

    // ---- MFMA: 4 ksteps x 4 frag-MFMAs ----
    __builtin_amdgcn_s_setprio(1);
    #pragma unroll
    for (int ks = 0; ks < 4; ++ks){
      acc00 = __builtin_amdgcn_mfma_f32_32x32x16_bf16(a0[ks].v, Bf[ks*2+0].v, acc00, 0, 0, 0);
      acc01 = __builtin_amdgcn_mfma_f32_32x32x16_bf16(a0[ks].v, Bf[ks*2+1].v, acc01, 0, 0, 0);
      acc10 = __builtin_amdgcn_mfma_f32_32x32x16_bf16(a1[ks].v, Bf[ks*2+0].v, acc10, 0, 0, 0);
      acc11 = __builtin_amdgcn_mfma_f32_32x32x16_bf16(a1[ks].v, Bf[ks*2+1].v, acc11, 0, 0, 0);
    }
    __builtin_amdgcn_s_setprio(0);
  }

  // ---- cross-wave K reduction via LDS ----
  {
    const int rowadd = 4 * kh;
    #pragma unroll
    for (int r = 0; r < 16; ++r){
      int rl = (r & 3) + 8 * (r >> 2) + rowadd;              // 32x32 C/D layout
      red[kv * 4096 + (rl)      * 64 + colb     ] = acc00[r];
      red[kv * 4096 + (rl)      * 64 + colb + 32] = acc01[r];
      red[kv * 4096 + (rl + 32) * 64 + colb     ] = acc10[r];
      red[kv * 4096 + (rl + 32) * 64 + colb + 32] = acc11[r];
    }
  }
  __syncthreads();
  const float bias = bias_w[h0];
  float* outp = out + (size_t)b * 262144 + (size_t)h0 * 4096;
  #pragma unroll
  for (int j = 0; j < 8; ++j){
    int oidx = j * 512 + tid;                  // px*64 + o, coalesced
    float v = bias;
    #pragma unroll
    for (int kvv = 0; kvv < 8; ++kvv) v += red[kvv * 4096 + oidx];
    outp[oidx] = v;
  }
}

extern "C" void kernel_launch(void* const* d_in, const int* in_sizes, int n_in,
                              void* d_out, int out_size, void* d_ws, size_t ws_size,
                              hipStream_t stream){
  const float* x      = (const float*)d_in[0];
  const float* W1     = (const float*)d_in[1];
  const float* W2     = (const float*)d_in[2];
  const float* bias_w = (const float*)d_in[3];
  float* out = (float*)d_out;
  (void)d_ws; (void)ws_size;

  volt_main<<<256, 512, 0, stream>>>(x, W1, W2, bias_w, out);
}

// Round 10
// 25.269 us; speedup vs baseline: 1.0519x; 1.0519x over previous
//
#include <hip/hip_runtime.h>
#include <hip/hip_bf16.h>

// Volterra conv (K=3, orders 1+2) as one fused bf16 MFMA GEMM:
// out[b, l, o] = sum_{c,f} A[l, c*64+f] * Wc[c*64+f, o]
//   f<9: linear xp[f]; 9<=f<54: xp[P]*xp[Q]/sqrt(45) (scale folded into Bpack); f>=54: 0
// Flat out = b*262144 + h_pix*4096 + w_pix*64 + o; bias = bias_w[h_pix] (zeros).
//
// r10: r4 grid/wave structure (grid 256=(b,h), 512 thr = 8 waves, K-split 8 ch/wave,
// permlane half-exchange, LDS-only final reduction) + r3's PROVEN-correct async
// mechanism (global_load_lds into wave-private LDS dbuf; in-flight data lives in
// LDS, untouchable by regalloc -- the r9 NaN was reg-copy of in-flight "=v" asm
// outputs) + T4 counted vmcnt(11) instead of drain (all 11 vmem ops per channel
// are intrinsics in deterministic order; x rows also staged via global_load_lds
// size-4 so no compiler-owned loads corrupt the count). No in-loop barriers.

typedef __bf16 bf16x8 __attribute__((ext_vector_type(8)));
typedef float f32x16 __attribute__((ext_vector_type(16)));

#define SCALE_Q 0.14907119849998599f  // 1/sqrt(45)

__device__ __constant__ int g_pairP[45] = {
  0,0,0,0,0,0,0,0,0, 1,1,1,1,1,1,1,1, 2,2,2,2,2,2,2,
  3,3,3,3,3,3, 4,4,4,4,4, 5,5,5,5, 6,6,6, 7,7, 8};
__device__ __constant__ int g_pairQ[45] = {
  0,1,2,3,4,5,6,7,8, 1,2,3,4,5,6,7,8, 2,3,4,5,6,7,8,
  3,4,5,6,7,8, 4,5,6,7,8, 5,6,7,8, 6,7,8, 7,8, 8};

union AFrag { unsigned int u[4]; bf16x8 v; };

__device__ inline unsigned int pack_bf16x2(float a, float b){
  union { __hip_bfloat16 h; unsigned short s; } ca, cb;
  ca.h = __float2bfloat16(a);
  cb.h = __float2bfloat16(b);
  return (unsigned int)ca.s | ((unsigned int)cb.s << 16);
}

// half-exchange: U = own k-low dword, V = own k-high dword ->
// o0 = frag word for output rows 0..31, o1 = for rows 32..63.
__device__ inline void half_swap(unsigned int U, unsigned int V,
                                 unsigned int& o0, unsigned int& o1, int lane){
#if __has_builtin(__builtin_amdgcn_permlane32_swap)
  auto rr = __builtin_amdgcn_permlane32_swap(U, V, false, false);
  o0 = rr[0]; o1 = rr[1];
#else
  unsigned int Ux = (unsigned int)__shfl_xor((int)U, 32);
  unsigned int Vx = (unsigned int)__shfl_xor((int)V, 32);
  const bool hi = (lane >= 32);
  o0 = hi ? Vx : U;
  o1 = hi ? V : Ux;
#endif
}

#define WAIT_VM(N) \
  do { asm volatile("s_waitcnt vmcnt(" #N ")" ::: "memory"); \
       __builtin_amdgcn_sched_barrier(0); } while (0)

#define GL2LDS(gsrc, ldst, SZ) \
  __builtin_amdgcn_global_load_lds( \
    (const __attribute__((address_space(1))) void*)(const void*)(gsrc), \
    (__attribute__((address_space(3))) void*)(void*)(ldst), SZ, 0, 0)

// ---------------- prep: pack weights into MFMA B-fragment order ----------------
// chunk g: c=g>>9; inner=g&511=(ks*2+nb)*64+lane;
// chunk (8 bf16) = B[k-slot = ks*16+(lane>>5)*8+j][n = nb*32+(lane&31)]
__global__ __launch_bounds__(256) void volt_pack(const float* __restrict__ W1,
                                                 const float* __restrict__ W2,
                                                 __hip_bfloat16* __restrict__ Bpack){
  int g = blockIdx.x * 256 + threadIdx.x;      // 0..32767
  int c     = g >> 9;
  int inner = g & 511;
  int lane  = inner & 63;
  int ks    = inner >> 7;
  int nb    = (inner >> 6) & 1;
  int n     = nb * 32 + (lane & 31);
  int kh    = lane >> 5;
  #pragma unroll
  for (int j = 0; j < 8; ++j){
    int f = ks * 16 + kh * 8 + j;
    float wv = 0.0f;
    if (f < 9)       wv = W1[(c * 9 + f) * 64 + n];
    else if (f < 54){
      int t = f - 9;
      wv = SCALE_Q * W2[(c * 81 + g_pairP[t] * 9 + g_pairQ[t]) * 64 + n];
    }
    Bpack[(size_t)g * 8 + j] = __float2bfloat16(wv);
  }
}

// ---------------- main fused kernel ----------------
// Per-wave LDS slice: 2 buffers x 9216 B  = {8192 B B-frags, 768 B x-rows, pad}.
__global__ __launch_bounds__(512, 2) void volt_main(const float* __restrict__ x,
                                                    const uint4* __restrict__ Bpack,
                                                    const float* __restrict__ bias_w,
                                                    float* __restrict__ out){
  __shared__ alignas(16) char smem[147456];    // 8 waves x 2 x 9216; reused for reduction
  const int tid  = threadIdx.x;
  const int lane = tid & 63;
  const int kv   = tid >> 6;                   // wave 0..7, channels kv*8..kv*8+7
  const int b    = blockIdx.x >> 6;
  const int h0   = blockIdx.x & 63;

  const int hm = (h0 > 0)  ? h0 - 1 : 0;       // clamped; masked on read
  const int hp = (h0 < 63) ? h0 + 1 : 63;
  const float* xw   = x + ((size_t)(b * 64 + kv * 8)) * 4096;
  const uint4* bsrc = Bpack + (size_t)(kv * 8) * 512 + lane;
  char* mylds = smem + kv * 18432;

  constexpr int kP[45] = {
    0,0,0,0,0,0,0,0,0, 1,1,1,1,1,1,1,1, 2,2,2,2,2,2,2,
    3,3,3,3,3,3, 4,4,4,4,4, 5,5,5,5, 6,6,6, 7,7, 8};
  constexpr int kQ[45] = {
    0,1,2,3,4,5,6,7,8, 1,2,3,4,5,6,7,8, 2,3,4,5,6,7,8,
    3,4,5,6,7,8, 4,5,6,7,8, 5,6,7,8, 6,7,8, 7,8, 8};

  f32x16 acc00{}, acc01{}, acc10{}, acc11{};   // [row-half][col-half]

  // issue one channel's 11 vmem ops (8 B-chunks + 3 x-rows), all to LDS, in order
  auto issueCh = [&](int ch, int buf){
    const uint4* s = bsrc + (size_t)ch * 512;
    char* db = mylds + buf * 9216;
    #pragma unroll
    for (int j = 0; j < 8; ++j) GL2LDS(s + j * 64, db + j * 1024, 16);
    const float* xc = xw + (size_t)ch * 4096;
    char* xb = db + 8192;
    GL2LDS(xc + hm * 64 + lane, xb + 0,   4);
    GL2LDS(xc + h0 * 64 + lane, xb + 256, 4);
    GL2LDS(xc + hp * 64 + lane, xb + 512, 4);
  };

  // one channel's feature-build + 16 MFMAs, reading B and x from LDS buf
  auto compute = [&](int buf){
    const char*  db = mylds + buf * 9216;
    const float* xb = reinterpret_cast<const float*>(db + 8192);
    const int lm = (lane == 0)  ? 0  : lane - 1;
    const int lp = (lane == 63) ? 63 : lane + 1;

    float xp[9];
    #pragma unroll
    for (int dh = 0; dh < 3; ++dh){
      float vL = xb[dh * 64 + lm];
      float vM = xb[dh * 64 + lane];
      float vR = xb[dh * 64 + lp];
      if (dh == 0 && h0 == 0)  { vL = 0.f; vM = 0.f; vR = 0.f; }
      if (dh == 2 && h0 == 63) { vL = 0.f; vM = 0.f; vR = 0.f; }
      xp[dh * 3 + 0] = (lane == 0)  ? 0.f : vL;
      xp[dh * 3 + 1] = vM;
      xp[dh * 3 + 2] = (lane == 63) ? 0.f : vR;
    }
    float pr[45];
    #pragma unroll
    for (int t = 0; t < 45; ++t) pr[t] = xp[kP[t]] * xp[kQ[t]];

    AFrag a0[4], a1[4];
    #pragma unroll
    for (int ks = 0; ks < 4; ++ks){
      unsigned int dl[8];                      // slots ks*16+0..15 as 8 dwords
      #pragma unroll
      for (int e = 0; e < 8; ++e){
        const int f0 = ks * 16 + 2 * e, f1 = f0 + 1;   // constants after unroll
        float va = (f0 < 9) ? xp[f0] : ((f0 < 54) ? pr[f0 - 9] : 0.0f);
        float vb = (f1 < 9) ? xp[f1] : ((f1 < 54) ? pr[f1 - 9] : 0.0f);
        dl[e] = pack_bf16x2(va, vb);
      }
      #pragma unroll
      for (int j = 0; j < 4; ++j){
        half_swap(dl[j], dl[4 + j], a0[ks].u[j], a1[ks].u[j], lane);
      }
    }

    __builtin_amdgcn_s_setprio(1);
    #pragma unroll
    for (int ks = 0; ks < 4; ++ks){
      bf16x8 b0 = *reinterpret_cast<const bf16x8*>(db + ((ks * 2 + 0) * 64 + lane) * 16);
      bf16x8 b1 = *reinterpret_cast<const bf16x8*>(db + ((ks * 2 + 1) * 64 + lane) * 16);
      acc00 = __builtin_amdgcn_mfma_f32_32x32x16_bf16(a0[ks].v, b0, acc00, 0, 0, 0);
      acc01 = __builtin_amdgcn_mfma_f32_32x32x16_bf16(a0[ks].v, b1, acc01, 0, 0, 0);
      acc10 = __builtin_amdgcn_mfma_f32_32x32x16_bf16(a1[ks].v, b0, acc10, 0, 0, 0);
      acc11 = __builtin_amdgcn_mfma_f32_32x32x16_bf16(a1[ks].v, b1, acc11, 0, 0, 0);
    }
    __builtin_amdgcn_s_setprio(0);
  };

  // ---- 2-deep ping-pong pipeline, counted vmcnt, no barriers ----
  issueCh(0, 0);                               // out = 11
  #pragma unroll 1
  for (int ii = 0; ii < 3; ++ii){
    issueCh(2 * ii + 1, 1);                    // out = 22
    WAIT_VM(11);                               // ch 2ii staged; 2ii+1 in flight
    compute(0);
    issueCh(2 * ii + 2, 0);                    // out = 22
    WAIT_VM(11);                               // ch 2ii+1 staged; 2ii+2 in flight
    compute(1);
  }
  issueCh(7, 1);                               // out = 22
  WAIT_VM(11);                                 // ch 6 staged
  compute(0);
  WAIT_VM(0);                                  // ch 7 staged
  compute(1);

  // ---- cross-wave K reduction via LDS (reuse smem) ----
  __syncthreads();                             // staging slices dead from here
  float* red = reinterpret_cast<float*>(smem);
  {
    const int colbase = lane & 31;
    const int rowadd  = 4 * (lane >> 5);
    #pragma unroll
    for (int r = 0; r < 16; ++r){
      int rl = (r & 3) + 8 * (r >> 2) + rowadd;              // 32x32 C/D layout
      red[kv * 4096 + (rl)      * 64 + colbase     ] = acc00[r];
      red[kv * 4096 + (rl)      * 64 + colbase + 32] = acc01[r];
      red[kv * 4096 + (rl + 32) * 64 + colbase     ] = acc10[r];
      red[kv * 4096 + (rl + 32) * 64 + colbase + 32] = acc11[r];
    }
  }
  __syncthreads();
  const float bias = bias_w[h0];
  float* outp = out + (size_t)b * 262144 + (size_t)h0 * 4096;
  #pragma unroll
  for (int j = 0; j < 8; ++j){
    int oidx = j * 512 + tid;                  // px*64 + o, coalesced
    float v = bias;
    #pragma unroll
    for (int kvv = 0; kvv < 8; ++kvv) v += red[kvv * 4096 + oidx];
    outp[oidx] = v;
  }
}

extern "C" void kernel_launch(void* const* d_in, const int* in_sizes, int n_in,
                              void* d_out, int out_size, void* d_ws, size_t ws_size,
                              hipStream_t stream){
  const float* x      = (const float*)d_in[0];
  const float* W1     = (const float*)d_in[1];
  const float* W2     = (const float*)d_in[2];
  const float* bias_w = (const float*)d_in[3];
  float* out = (float*)d_out;
  __hip_bfloat16* Bpack = (__hip_bfloat16*)d_ws;   // 512 KB

  volt_pack<<<128, 256, 0, stream>>>(W1, W2, Bpack);
  volt_main<<<256, 512, 0, stream>>>(x, (const uint4*)d_ws, bias_w, out);
}

// Round 11
// 23.794 us; speedup vs baseline: 1.1171x; 1.0620x over previous
//
#include <hip/hip_runtime.h>
#include <hip/hip_bf16.h>

// Volterra conv (K=3, orders 1+2) as one fused bf16 MFMA GEMM:
// out[b, l, o] = sum_{c,f} A[l, c*64+f] * Wc[c*64+f, o]
//   f<9: linear xp[f]; 9<=f<54: xp[P]*xp[Q]/sqrt(45) (scale folded into Bpack); f>=54: 0
// Flat out = b*262144 + h_pix*4096 + w_pix*64 + o; bias = bias_w[h_pix] (zeros).
//
// r11: OCCUPANCY round. All prior variants ran <=2 waves/SIMD and sat ~75% idle
// with VALU:MFMA busy ratio matching the static mix (=> dependency-latency bound,
// not bandwidth/sync bound). r11 = r4 mapping with 16 waves/wg (1024 thr), still
// grid 256 = 1 wg/CU (B-traffic stays 128 MB), K-split 4 ch/wave, 4 waves/SIMD.
// VGPR diet to fit 128: per-ks A-frag build (no d[32]/pr[45]), compiler-scheduled
// B loads, 2-stage LDS reduction (waves 8-15 dump 128KB, waves 0-7 merge, all store).

typedef __bf16 bf16x8 __attribute__((ext_vector_type(8)));
typedef float f32x16 __attribute__((ext_vector_type(16)));

#define SCALE_Q 0.14907119849998599f  // 1/sqrt(45)

__device__ __constant__ int g_pairP[45] = {
  0,0,0,0,0,0,0,0,0, 1,1,1,1,1,1,1,1, 2,2,2,2,2,2,2,
  3,3,3,3,3,3, 4,4,4,4,4, 5,5,5,5, 6,6,6, 7,7, 8};
__device__ __constant__ int g_pairQ[45] = {
  0,1,2,3,4,5,6,7,8, 1,2,3,4,5,6,7,8, 2,3,4,5,6,7,8,
  3,4,5,6,7,8, 4,5,6,7,8, 5,6,7,8, 6,7,8, 7,8, 8};

constexpr int cP[45] = {
  0,0,0,0,0,0,0,0,0, 1,1,1,1,1,1,1,1, 2,2,2,2,2,2,2,
  3,3,3,3,3,3, 4,4,4,4,4, 5,5,5,5, 6,6,6, 7,7, 8};
constexpr int cQ[45] = {
  0,1,2,3,4,5,6,7,8, 1,2,3,4,5,6,7,8, 2,3,4,5,6,7,8,
  3,4,5,6,7,8, 4,5,6,7,8, 5,6,7,8, 6,7,8, 7,8, 8};

union AFrag { unsigned int u[4]; bf16x8 v; };
union BFrag { uint4 q; bf16x8 v; };

__device__ inline unsigned int pack_bf16x2(float a, float b){
  union { __hip_bfloat16 h; unsigned short s; } ca, cb;
  ca.h = __float2bfloat16(a);
  cb.h = __float2bfloat16(b);
  return (unsigned int)ca.s | ((unsigned int)cb.s << 16);
}

// half-exchange: U = own k-low dword, V = own k-high dword ->
// o0 = frag word for output rows 0..31, o1 = for rows 32..63.
__device__ inline void half_swap(unsigned int U, unsigned int V,
                                 unsigned int& o0, unsigned int& o1, int lane){
#if __has_builtin(__builtin_amdgcn_permlane32_swap)
  auto rr = __builtin_amdgcn_permlane32_swap(U, V, false, false);
  o0 = rr[0]; o1 = rr[1];
#else
  unsigned int Ux = (unsigned int)__shfl_xor((int)U, 32);
  unsigned int Vx = (unsigned int)__shfl_xor((int)V, 32);
  const bool hi = (lane >= 32);
  o0 = hi ? Vx : U;
  o1 = hi ? V : Ux;
#endif
}

// slot value; F is a compile-time constant after full unroll
__device__ inline float slotv(int F, const float (&xp)[9]){
  if (F < 9)  return xp[F];
  if (F < 54) return xp[cP[F - 9]] * xp[cQ[F - 9]];
  return 0.0f;
}

// ---------------- prep: pack weights into MFMA B-fragment order ----------------
// chunk g: c=g>>9; inner=g&511=(ks*2+nb)*64+lane;
// chunk (8 bf16) = B[k-slot = ks*16+(lane>>5)*8+j][n = nb*32+(lane&31)]
__global__ __launch_bounds__(256) void volt_pack(const float* __restrict__ W1,
                                                 const float* __restrict__ W2,
                                                 __hip_bfloat16* __restrict__ Bpack){
  int g = blockIdx.x * 256 + threadIdx.x;      // 0..32767
  int c     = g >> 9;
  int inner = g & 511;
  int lane  = inner & 63;
  int ks    = inner >> 7;
  int nb    = (inner >> 6) & 1;
  int n     = nb * 32 + (lane & 31);
  int kh    = lane >> 5;
  #pragma unroll
  for (int j = 0; j < 8; ++j){
    int f = ks * 16 + kh * 8 + j;
    float wv = 0.0f;
    if (f < 9)       wv = W1[(c * 9 + f) * 64 + n];
    else if (f < 54){
      int t = f - 9;
      wv = SCALE_Q * W2[(c * 81 + g_pairP[t] * 9 + g_pairQ[t]) * 64 + n];
    }
    Bpack[(size_t)g * 8 + j] = __float2bfloat16(wv);
  }
}

// ---------------- main fused kernel ----------------
__global__ __launch_bounds__(1024, 4) void volt_main(const float* __restrict__ x,
                                                     const uint4* __restrict__ Bpack,
                                                     const float* __restrict__ bias_w,
                                                     float* __restrict__ out){
  __shared__ float red[8 * 4096];              // 128 KB
  const int tid  = threadIdx.x;
  const int lane = tid & 63;
  const int kv   = tid >> 6;                   // wave 0..15, channels kv*4..kv*4+3
  const int b    = blockIdx.x >> 6;
  const int h0   = blockIdx.x & 63;

  const int hm = (h0 > 0)  ? h0 - 1 : 0;       // clamped; masked in build
  const int hp = (h0 < 63) ? h0 + 1 : 63;
  const float* xw   = x + ((size_t)(b * 64 + kv * 4)) * 4096;
  const uint4* bsrc = Bpack + (size_t)(kv * 4) * 512 + lane;

  f32x16 acc00{}, acc01{}, acc10{}, acc11{};   // [row-half][col-half]

  #pragma unroll
  for (int i = 0; i < 4; ++i){
    // ---- x rows for this channel ----
    const float* xc = xw + (size_t)i * 4096;
    float cx0 = xc[hm * 64 + lane];
    float cx1 = xc[h0 * 64 + lane];
    float cx2 = xc[hp * 64 + lane];

    // ---- xp[9] for this lane's pixel (w = lane) ----
    float xp[9];
    {
      float rows[3] = {cx0, cx1, cx2};
      #pragma unroll
      for (int dh = 0; dh < 3; ++dh){
        float mid = rows[dh];
        if (dh == 0 && h0 == 0)  mid = 0.f;    // wave-uniform row clamp
        if (dh == 2 && h0 == 63) mid = 0.f;
        float lf = __shfl(mid, lane - 1);
        float rt = __shfl(mid, lane + 1);
        xp[dh * 3 + 0] = (lane == 0)  ? 0.f : lf;
        xp[dh * 3 + 1] = mid;
        xp[dh * 3 + 2] = (lane == 63) ? 0.f : rt;
      }
    }

    const uint4* s = bsrc + (size_t)i * 512;

    // ---- per-kstep: build 16 slots, exchange, 4 MFMAs (low register footprint) ----
    #pragma unroll
    for (int ks = 0; ks < 4; ++ks){
      BFrag B0, B1;
      B0.q = s[(ks * 2 + 0) * 64];
      B1.q = s[(ks * 2 + 1) * 64];

      unsigned int dl[8];                      // slots ks*16 + 0..15
      #pragma unroll
      for (int e = 0; e < 8; ++e){
        const int f0 = ks * 16 + 2 * e;        // compile-time after unroll
        dl[e] = pack_bf16x2(slotv(f0, xp), slotv(f0 + 1, xp));
      }
      AFrag a0, a1;
      #pragma unroll
      for (int j = 0; j < 4; ++j){
        half_swap(dl[j], dl[4 + j], a0.u[j], a1.u[j], lane);
      }

      __builtin_amdgcn_s_setprio(1);
      acc00 = __builtin_amdgcn_mfma_f32_32x32x16_bf16(a0.v, B0.v, acc00, 0, 0, 0);
      acc01 = __builtin_amdgcn_mfma_f32_32x32x16_bf16(a0.v, B1.v, acc01, 0, 0, 0);
      acc10 = __builtin_amdgcn_mfma_f32_32x32x16_bf16(a1.v, B0.v, acc10, 0, 0, 0);
      acc11 = __builtin_amdgcn_mfma_f32_32x32x16_bf16(a1.v, B1.v, acc11, 0, 0, 0);
      __builtin_amdgcn_s_setprio(0);
    }
  }

  // ---- 2-stage cross-wave K reduction via LDS (16 waves, 8 buffers) ----
  const int colbase = lane & 31;
  const int rowadd  = 4 * (lane >> 5);
  float* buf = red + (kv & 7) * 4096;

  if (kv >= 8){                                // stage A: upper waves dump
    #pragma unroll
    for (int r = 0; r < 16; ++r){
      int rl = (r & 3) + 8 * (r >> 2) + rowadd;              // 32x32 C/D layout
      buf[(rl)      * 64 + colbase     ] = acc00[r];
      buf[(rl)      * 64 + colbase + 32] = acc01[r];
      buf[(rl + 32) * 64 + colbase     ] = acc10[r];
      buf[(rl + 32) * 64 + colbase + 32] = acc11[r];
    }
  }
  __syncthreads();
  if (kv < 8){                                 // stage B: lower waves merge + dump
    #pragma unroll
    for (int r = 0; r < 16; ++r){
      int rl = (r & 3) + 8 * (r >> 2) + rowadd;
      buf[(rl)      * 64 + colbase     ] += acc00[r];
      buf[(rl)      * 64 + colbase + 32] += acc01[r];
      buf[(rl + 32) * 64 + colbase     ] += acc10[r];
      buf[(rl + 32) * 64 + colbase + 32] += acc11[r];
    }
  }
  __syncthreads();
  const float bias = bias_w[h0];
  float* outp = out + (size_t)b * 262144 + (size_t)h0 * 4096;
  #pragma unroll
  for (int j = 0; j < 4; ++j){
    int oidx = j * 1024 + tid;                 // px*64 + o, coalesced
    float v = bias;
    #pragma unroll
    for (int kvv = 0; kvv < 8; ++kvv) v += red[kvv * 4096 + oidx];
    outp[oidx] = v;
  }
}

extern "C" void kernel_launch(void* const* d_in, const int* in_sizes, int n_in,
                              void* d_out, int out_size, void* d_ws, size_t ws_size,
                              hipStream_t stream){
  const float* x      = (const float*)d_in[0];
  const float* W1     = (const float*)d_in[1];
  const float* W2     = (const float*)d_in[2];
  const float* bias_w = (const float*)d_in[3];
  float* out = (float*)d_out;
  __hip_bfloat16* Bpack = (__hip_bfloat16*)d_ws;   // 512 KB

  volt_pack<<<128, 256, 0, stream>>>(W1, W2, Bpack);
  volt_main<<<256, 1024, 0, stream>>>(x, (const uint4*)d_ws, bias_w, out);
}

// Round 12
// 22.237 us; speedup vs baseline: 1.1954x; 1.0700x over previous
//
#include <hip/hip_runtime.h>
#include <hip/hip_bf16.h>

// Volterra conv (K=3, orders 1+2) as one fused bf16 MFMA GEMM:
// out[b, l, o] = sum_{c,f} A[l, c*64+f] * Wc[c*64+f, o]
//   f<9: linear xp[f]; 9<=f<54: xp[P]*xp[Q]/sqrt(45) (scale folded into Bpack); f>=54: 0
// Flat out = b*262144 + h_pix*4096 + w_pix*64 + o; bias = bias_w[h_pix] (zeros).
//
// r12 = r4 (best known, 22.7us) + VALU diet:
//   (1) bf16 packing via HW v_cvt_pk_bf16_f32 (1 inst / 2 floats) instead of
//       __float2bfloat16 (software RNE + NaN path, ~5-8 VALU each).  64 casts per
//       channel per lane was the largest invisible VALU component (profiles show
//       VALUBusy*dur ~= 7.5-9us invariant across r2-r11, ~3x the hand-count).
//   (2) volt_pack stores one coalesced uint4 instead of 8 scalar 2B stores.

typedef __bf16 bf16x8 __attribute__((ext_vector_type(8)));
typedef float f32x16 __attribute__((ext_vector_type(16)));

#define SCALE_Q 0.14907119849998599f  // 1/sqrt(45)

__device__ __constant__ int g_pairP[45] = {
  0,0,0,0,0,0,0,0,0, 1,1,1,1,1,1,1,1, 2,2,2,2,2,2,2,
  3,3,3,3,3,3, 4,4,4,4,4, 5,5,5,5, 6,6,6, 7,7, 8};
__device__ __constant__ int g_pairQ[45] = {
  0,1,2,3,4,5,6,7,8, 1,2,3,4,5,6,7,8, 2,3,4,5,6,7,8,
  3,4,5,6,7,8, 4,5,6,7,8, 5,6,7,8, 6,7,8, 7,8, 8};

union AFrag { unsigned int u[4]; bf16x8 v; };
union BFrag { uint4 q; bf16x8 v; };

// HW packed f32->bf16 (RNE), 1 VALU inst for 2 values. Non-volatile: schedulable.
__device__ inline unsigned int pack_bf16x2(float a, float b){
  unsigned int r;
  asm("v_cvt_pk_bf16_f32 %0, %1, %2" : "=v"(r) : "v"(a), "v"(b));
  return r;
}

// half-exchange: U = own k-low dword, V = own k-high dword ->
// o0 = frag word for output rows 0..31, o1 = for rows 32..63.
__device__ inline void half_swap(unsigned int U, unsigned int V,
                                 unsigned int& o0, unsigned int& o1, int lane){
#if __has_builtin(__builtin_amdgcn_permlane32_swap)
  auto rr = __builtin_amdgcn_permlane32_swap(U, V, false, false);
  o0 = rr[0]; o1 = rr[1];
#else
  unsigned int Ux = (unsigned int)__shfl_xor((int)U, 32);
  unsigned int Vx = (unsigned int)__shfl_xor((int)V, 32);
  const bool hi = (lane >= 32);
  o0 = hi ? Vx : U;
  o1 = hi ? V : Ux;
#endif
}

// ---------------- prep: pack weights into MFMA B-fragment order ----------------
// chunk g: c=g>>9; inner=g&511=(ks*2+nb)*64+lane;
// chunk (8 bf16) = B[k-slot = ks*16+(lane>>5)*8+j][n = nb*32+(lane&31)]
__global__ __launch_bounds__(256) void volt_pack(const float* __restrict__ W1,
                                                 const float* __restrict__ W2,
                                                 uint4* __restrict__ Bpack){
  int g = blockIdx.x * 256 + threadIdx.x;      // 0..32767
  int c     = g >> 9;
  int inner = g & 511;
  int lane  = inner & 63;
  int ks    = inner >> 7;
  int nb    = (inner >> 6) & 1;
  int n     = nb * 32 + (lane & 31);
  int kh    = lane >> 5;
  float wv[8];
  #pragma unroll
  for (int j = 0; j < 8; ++j){
    int f = ks * 16 + kh * 8 + j;
    float v = 0.0f;
    if (f < 9)       v = W1[(c * 9 + f) * 64 + n];
    else if (f < 54){
      int t = f - 9;
      v = SCALE_Q * W2[(c * 81 + g_pairP[t] * 9 + g_pairQ[t]) * 64 + n];
    }
    wv[j] = v;
  }
  uint4 o;
  o.x = pack_bf16x2(wv[0], wv[1]);
  o.y = pack_bf16x2(wv[2], wv[3]);
  o.z = pack_bf16x2(wv[4], wv[5]);
  o.w = pack_bf16x2(wv[6], wv[7]);
  Bpack[g] = o;                                // coalesced 16B store
}

// ---------------- main fused kernel ----------------
__global__ __launch_bounds__(512, 2) void volt_main(const float* __restrict__ x,
                                                    const uint4* __restrict__ Bpack,
                                                    const float* __restrict__ bias_w,
                                                    float* __restrict__ out){
  __shared__ float red[8 * 4096];              // 128 KB: per-wave partial 64x64 tiles
  const int tid  = threadIdx.x;
  const int lane = tid & 63;
  const int kv   = tid >> 6;                   // wave 0..7, channels kv*8..kv*8+7
  const int b    = blockIdx.x >> 6;
  const int h0   = blockIdx.x & 63;

  const int hm = (h0 > 0)  ? h0 - 1 : 0;       // clamped; masked in build
  const int hp = (h0 < 63) ? h0 + 1 : 63;
  const float* xw   = x + ((size_t)(b * 64 + kv * 8)) * 4096;
  const uint4* bsrc = Bpack + (size_t)(kv * 8) * 512 + lane;

  constexpr int kP[45] = {
    0,0,0,0,0,0,0,0,0, 1,1,1,1,1,1,1,1, 2,2,2,2,2,2,2,
    3,3,3,3,3,3, 4,4,4,4,4, 5,5,5,5, 6,6,6, 7,7, 8};
  constexpr int kQ[45] = {
    0,1,2,3,4,5,6,7,8, 1,2,3,4,5,6,7,8, 2,3,4,5,6,7,8,
    3,4,5,6,7,8, 4,5,6,7,8, 5,6,7,8, 6,7,8, 7,8, 8};

  f32x16 acc00{}, acc01{}, acc10{}, acc11{};   // [row-half][col-half]

  // register-resident B (current channel) + x rows (current channel)
  BFrag curB[8];
  float cx[3];
  #pragma unroll
  for (int j = 0; j < 8; ++j) curB[j].q = bsrc[j * 64];
  cx[0] = xw[hm * 64 + lane];
  cx[1] = xw[h0 * 64 + lane];
  cx[2] = xw[hp * 64 + lane];

  #pragma unroll
  for (int i = 0; i < 8; ++i){                 // full unroll: all indexing static
    BFrag nxtB[8];
    float nx2[3];
    if (i < 7){                                // issue prefetch before any waits
      const uint4* s = bsrc + (size_t)(i + 1) * 512;
      #pragma unroll
      for (int j = 0; j < 8; ++j) nxtB[j].q = s[j * 64];
      const float* xc = xw + (size_t)(i + 1) * 4096;
      nx2[0] = xc[hm * 64 + lane];
      nx2[1] = xc[h0 * 64 + lane];
      nx2[2] = xc[hp * 64 + lane];
    }

    // ---- features for this lane's pixel (w_pix = lane) ----
    float xp[9];
    #pragma unroll
    for (int dh = 0; dh < 3; ++dh){
      float mid = cx[dh];
      if (dh == 0 && h0 == 0)  mid = 0.f;      // wave-uniform row clamp
      if (dh == 2 && h0 == 63) mid = 0.f;
      float lf = __shfl(mid, lane - 1);
      float rt = __shfl(mid, lane + 1);
      xp[dh * 3 + 0] = (lane == 0)  ? 0.f : lf;
      xp[dh * 3 + 1] = mid;
      xp[dh * 3 + 2] = (lane == 63) ? 0.f : rt;
    }
    float pr[45];
    #pragma unroll
    for (int t = 0; t < 45; ++t) pr[t] = xp[kP[t]] * xp[kQ[t]];

    unsigned int d[32];                        // 64 bf16 feature slots as dwords
    #pragma unroll
    for (int s = 0; s < 32; ++s){
      const int f0 = 2 * s, f1 = 2 * s + 1;
      float a  = (f0 < 9) ? xp[f0] : ((f0 < 54) ? pr[f0 - 9] : 0.0f);
      float b2 = (f1 < 9) ? xp[f1] : ((f1 < 54) ? pr[f1 - 9] : 0.0f);
      d[s] = pack_bf16x2(a, b2);
    }

    // ---- A-frag half-exchange ----
    AFrag a0[4], a1[4];
    #pragma unroll
    for (int ks = 0; ks < 4; ++ks){
      #pragma unroll
      for (int j = 0; j < 4; ++j){
        half_swap(d[ks * 8 + j], d[ks * 8 + 4 + j], a0[ks].u[j], a1[ks].u[j], lane);
      }
    }

    // ---- MFMA: 4 ksteps x 4 frag-MFMAs from register B ----
    __builtin_amdgcn_s_setprio(1);
    #pragma unroll
    for (int ks = 0; ks < 4; ++ks){
      acc00 = __builtin_amdgcn_mfma_f32_32x32x16_bf16(a0[ks].v, curB[ks*2+0].v, acc00, 0, 0, 0);
      acc01 = __builtin_amdgcn_mfma_f32_32x32x16_bf16(a0[ks].v, curB[ks*2+1].v, acc01, 0, 0, 0);
      acc10 = __builtin_amdgcn_mfma_f32_32x32x16_bf16(a1[ks].v, curB[ks*2+0].v, acc10, 0, 0, 0);
      acc11 = __builtin_amdgcn_mfma_f32_32x32x16_bf16(a1[ks].v, curB[ks*2+1].v, acc11, 0, 0, 0);
    }
    __builtin_amdgcn_s_setprio(0);

    if (i < 7){
      #pragma unroll
      for (int j = 0; j < 8; ++j) curB[j] = nxtB[j];
      cx[0] = nx2[0]; cx[1] = nx2[1]; cx[2] = nx2[2];
    }
  }

  // ---- cross-wave K reduction via LDS ----
  {
    const int colbase = lane & 31;
    const int rowadd  = 4 * (lane >> 5);
    #pragma unroll
    for (int r = 0; r < 16; ++r){
      int rl = (r & 3) + 8 * (r >> 2) + rowadd;              // 32x32 C/D layout
      red[kv * 4096 + (rl)      * 64 + colbase     ] = acc00[r];
      red[kv * 4096 + (rl)      * 64 + colbase + 32] = acc01[r];
      red[kv * 4096 + (rl + 32) * 64 + colbase     ] = acc10[r];
      red[kv * 4096 + (rl + 32) * 64 + colbase + 32] = acc11[r];
    }
  }
  __syncthreads();
  const float bias = bias_w[h0];
  float* outp = out + (size_t)b * 262144 + (size_t)h0 * 4096;
  #pragma unroll
  for (int j = 0; j < 8; ++j){
    int oidx = j * 512 + tid;                  // px*64 + o, coalesced
    float v = bias;
    #pragma unroll
    for (int kvv = 0; kvv < 8; ++kvv) v += red[kvv * 4096 + oidx];
    outp[oidx] = v;
  }
}

extern "C" void kernel_launch(void* const* d_in, const int* in_sizes, int n_in,
                              void* d_out, int out_size, void* d_ws, size_t ws_size,
                              hipStream_t stream){
  const float* x      = (const float*)d_in[0];
  const float* W1     = (const float*)d_in[1];
  const float* W2     = (const float*)d_in[2];
  const float* bias_w = (const float*)d_in[3];
  float* out = (float*)d_out;
  uint4* Bpack = (uint4*)d_ws;                 // 512 KB

  volt_pack<<<128, 256, 0, stream>>>(W1, W2, Bpack);
  volt_main<<<256, 512, 0, stream>>>(x, (const uint4*)d_ws, bias_w, out);
}

// Round 13
// 21.061 us; speedup vs baseline: 1.2621x; 1.0558x over previous
//
#include <hip/hip_runtime.h>
#include <hip/hip_bf16.h>

// Volterra conv (K=3, orders 1+2) as one fused bf16 MFMA GEMM.
// r13 = r12 + CHANNEL-PAIR K-packing: two channels' 54+54 real feature slots are
// packed into 112 slots = 7 ksteps (vs 2x4 ksteps = 128 slots with 20 zeros).
// -12.5% on B bytes (Bpack 512->448 KB), MFMA count (128->112/wave), pack VALU.
// Slot map (compile-time after unroll): F<54 -> ch0 feature F; F<108 -> ch1
// feature F-54; F>=108 -> 0.  Feature g: g<9 linear xp[g]; else xp[P]*xp[Q]
// (1/sqrt(45) folded into Bpack).  Everything else = r12 (best known):
// grid 256=(b,h), 512 thr = 8 waves, K-split 8 ch = 4 pairs/wave, reg B dbuf,
// permlane half-exchange, HW cvt_pk_bf16, LDS-only final reduction.
// Flat out = b*262144 + h_pix*4096 + w_pix*64 + o; bias = bias_w[h_pix].

typedef __bf16 bf16x8 __attribute__((ext_vector_type(8)));
typedef float f32x16 __attribute__((ext_vector_type(16)));

#define SCALE_Q 0.14907119849998599f  // 1/sqrt(45)

__device__ __constant__ int g_pairP[45] = {
  0,0,0,0,0,0,0,0,0, 1,1,1,1,1,1,1,1, 2,2,2,2,2,2,2,
  3,3,3,3,3,3, 4,4,4,4,4, 5,5,5,5, 6,6,6, 7,7, 8};
__device__ __constant__ int g_pairQ[45] = {
  0,1,2,3,4,5,6,7,8, 1,2,3,4,5,6,7,8, 2,3,4,5,6,7,8,
  3,4,5,6,7,8, 4,5,6,7,8, 5,6,7,8, 6,7,8, 7,8, 8};

constexpr int cP[45] = {
  0,0,0,0,0,0,0,0,0, 1,1,1,1,1,1,1,1, 2,2,2,2,2,2,2,
  3,3,3,3,3,3, 4,4,4,4,4, 5,5,5,5, 6,6,6, 7,7, 8};
constexpr int cQ[45] = {
  0,1,2,3,4,5,6,7,8, 1,2,3,4,5,6,7,8, 2,3,4,5,6,7,8,
  3,4,5,6,7,8, 4,5,6,7,8, 5,6,7,8, 6,7,8, 7,8, 8};

union AFrag { unsigned int u[4]; bf16x8 v; };
union BFrag { uint4 q; bf16x8 v; };

// HW packed f32->bf16 (RNE), 1 VALU inst per 2 values.
__device__ inline unsigned int pack_bf16x2(float a, float b){
  unsigned int r;
  asm("v_cvt_pk_bf16_f32 %0, %1, %2" : "=v"(r) : "v"(a), "v"(b));
  return r;
}

// half-exchange: U = own k-low dword, V = own k-high dword ->
// o0 = frag word for output rows 0..31, o1 = for rows 32..63.
__device__ inline void half_swap(unsigned int U, unsigned int V,
                                 unsigned int& o0, unsigned int& o1, int lane){
#if __has_builtin(__builtin_amdgcn_permlane32_swap)
  auto rr = __builtin_amdgcn_permlane32_swap(U, V, false, false);
  o0 = rr[0]; o1 = rr[1];
#else
  unsigned int Ux = (unsigned int)__shfl_xor((int)U, 32);
  unsigned int Vx = (unsigned int)__shfl_xor((int)V, 32);
  const bool hi = (lane >= 32);
  o0 = hi ? Vx : U;
  o1 = hi ? V : Ux;
#endif
}

// pair-slot value; F compile-time constant after full unroll
__device__ inline float slotv(int F, const float (&xp0)[9], const float (&xp1)[9]){
  if (F < 54){  int g = F;      return (g < 9) ? xp0[g] : xp0[cP[g-9]] * xp0[cQ[g-9]]; }
  if (F < 108){ int g = F - 54; return (g < 9) ? xp1[g] : xp1[cP[g-9]] * xp1[cQ[g-9]]; }
  return 0.0f;
}

// ---------------- prep: pack weight channel-PAIRS into MFMA B-frag order ----------------
// chunk G in [0,448): pair Pg=G/14, rem=G%14, t=rem>>1 (kstep 0..6), nb=rem&1.
// chunk (8 bf16, lane kh=lane>>5, col=nb*32+(lane&31)) = B[F = t*16+kh*8+j][col]
__global__ __launch_bounds__(256) void volt_pack(const float* __restrict__ W1,
                                                 const float* __restrict__ W2,
                                                 uint4* __restrict__ Bpack){
  int gt   = blockIdx.x * 256 + threadIdx.x;   // 0..28671
  int G    = gt >> 6;
  int lane = gt & 63;
  int Pg   = G / 14;
  int rem  = G - Pg * 14;
  int t    = rem >> 1;
  int nb   = rem & 1;
  int n    = nb * 32 + (lane & 31);
  int kh   = lane >> 5;
  float wv[8];
  #pragma unroll
  for (int j = 0; j < 8; ++j){
    int F = t * 16 + kh * 8 + j;               // 0..111
    float v = 0.0f;
    if (F < 108){
      int c = 2 * Pg + (F >= 54 ? 1 : 0);
      int g = (F >= 54) ? F - 54 : F;
      if (g < 9) v = W1[(c * 9 + g) * 64 + n];
      else {
        int tt = g - 9;
        v = SCALE_Q * W2[(c * 81 + g_pairP[tt] * 9 + g_pairQ[tt]) * 64 + n];
      }
    }
    wv[j] = v;
  }
  uint4 o;
  o.x = pack_bf16x2(wv[0], wv[1]);
  o.y = pack_bf16x2(wv[2], wv[3]);
  o.z = pack_bf16x2(wv[4], wv[5]);
  o.w = pack_bf16x2(wv[6], wv[7]);
  Bpack[(size_t)G * 64 + lane] = o;            // coalesced 16B store
}

// ---------------- main fused kernel ----------------
__global__ __launch_bounds__(512, 2) void volt_main(const float* __restrict__ x,
                                                    const uint4* __restrict__ Bpack,
                                                    const float* __restrict__ bias_w,
                                                    float* __restrict__ out){
  __shared__ float red[8 * 4096];              // 128 KB: per-wave partial 64x64 tiles
  const int tid  = threadIdx.x;
  const int lane = tid & 63;
  const int kv   = tid >> 6;                   // wave 0..7, channels kv*8..kv*8+7 = pairs kv*4..kv*4+3
  const int b    = blockIdx.x >> 6;
  const int h0   = blockIdx.x & 63;

  const int hm = (h0 > 0)  ? h0 - 1 : 0;       // clamped; masked in build
  const int hp = (h0 < 63) ? h0 + 1 : 63;
  const float* xw   = x + ((size_t)(b * 64 + kv * 8)) * 4096;
  const uint4* bsrc = Bpack + (size_t)(kv * 4) * 896 + lane;   // 14 chunks x 64 uint4 per pair

  f32x16 acc00{}, acc01{}, acc10{}, acc11{};   // [row-half][col-half]

  // load one pair's 14 B-chunks + both channels' 3 x-rows
  auto loadPair = [&](int pp, BFrag (&B)[14], float (&c0)[3], float (&c1)[3]){
    const uint4* s = bsrc + (size_t)pp * 896;
    #pragma unroll
    for (int u = 0; u < 14; ++u) B[u].q = s[u * 64];
    const float* xc0 = xw + (size_t)(2 * pp) * 4096;
    const float* xc1 = xc0 + 4096;
    c0[0] = xc0[hm * 64 + lane];  c0[1] = xc0[h0 * 64 + lane];  c0[2] = xc0[hp * 64 + lane];
    c1[0] = xc1[hm * 64 + lane];  c1[1] = xc1[h0 * 64 + lane];  c1[2] = xc1[hp * 64 + lane];
  };

  auto buildXp = [&](const float (&cx)[3], float (&xp)[9]){
    #pragma unroll
    for (int dh = 0; dh < 3; ++dh){
      float mid = cx[dh];
      if (dh == 0 && h0 == 0)  mid = 0.f;      // wave-uniform row clamp
      if (dh == 2 && h0 == 63) mid = 0.f;
      float lf = __shfl(mid, lane - 1);
      float rt = __shfl(mid, lane + 1);
      xp[dh * 3 + 0] = (lane == 0)  ? 0.f : lf;
      xp[dh * 3 + 1] = mid;
      xp[dh * 3 + 2] = (lane == 63) ? 0.f : rt;
    }
  };

  // one PAIR: feature build + 7 ksteps x 4 MFMAs
  auto compute = [&](const float (&cx0)[3], const float (&cx1)[3], const BFrag (&Bf)[14]){
    float xp0[9], xp1[9];
    buildXp(cx0, xp0);
    buildXp(cx1, xp1);

    __builtin_amdgcn_s_setprio(1);
    #pragma unroll
    for (int t = 0; t < 7; ++t){
      unsigned int dl[8];                      // kh0: slots t*16+0..7; kh1: +8..15
      #pragma unroll
      for (int j = 0; j < 4; ++j){
        const int F0 = t * 16 + 2 * j;         // compile-time after unroll
        dl[j]     = pack_bf16x2(slotv(F0,     xp0, xp1), slotv(F0 + 1, xp0, xp1));
        dl[4 + j] = pack_bf16x2(slotv(F0 + 8, xp0, xp1), slotv(F0 + 9, xp0, xp1));
      }
      AFrag a0, a1;
      #pragma unroll
      for (int j = 0; j < 4; ++j){
        half_swap(dl[j], dl[4 + j], a0.u[j], a1.u[j], lane);
      }
      acc00 = __builtin_amdgcn_mfma_f32_32x32x16_bf16(a0.v, Bf[t*2+0].v, acc00, 0, 0, 0);
      acc01 = __builtin_amdgcn_mfma_f32_32x32x16_bf16(a0.v, Bf[t*2+1].v, acc01, 0, 0, 0);
      acc10 = __builtin_amdgcn_mfma_f32_32x32x16_bf16(a1.v, Bf[t*2+0].v, acc10, 0, 0, 0);
      acc11 = __builtin_amdgcn_mfma_f32_32x32x16_bf16(a1.v, Bf[t*2+1].v, acc11, 0, 0, 0);
    }
    __builtin_amdgcn_s_setprio(0);
  };

  // ---- pair loop: 4 pairs, register double-buffer, full unroll ----
  BFrag curB[14], nxtB[14];
  float cx0[3], cx1[3], nx0[3], nx1[3];
  loadPair(0, curB, cx0, cx1);

  #pragma unroll
  for (int pp = 0; pp < 4; ++pp){
    if (pp < 3) loadPair(pp + 1, nxtB, nx0, nx1);   // prefetch next pair
    compute(cx0, cx1, curB);
    if (pp < 3){
      #pragma unroll
      for (int u = 0; u < 14; ++u) curB[u] = nxtB[u];
      #pragma unroll
      for (int r = 0; r < 3; ++r){ cx0[r] = nx0[r]; cx1[r] = nx1[r]; }
    }
  }

  // ---- cross-wave K reduction via LDS ----
  {
    const int colbase = lane & 31;
    const int rowadd  = 4 * (lane >> 5);
    #pragma unroll
    for (int r = 0; r < 16; ++r){
      int rl = (r & 3) + 8 * (r >> 2) + rowadd;              // 32x32 C/D layout
      red[kv * 4096 + (rl)      * 64 + colbase     ] = acc00[r];
      red[kv * 4096 + (rl)      * 64 + colbase + 32] = acc01[r];
      red[kv * 4096 + (rl + 32) * 64 + colbase     ] = acc10[r];
      red[kv * 4096 + (rl + 32) * 64 + colbase + 32] = acc11[r];
    }
  }
  __syncthreads();
  const float bias = bias_w[h0];
  float* outp = out + (size_t)b * 262144 + (size_t)h0 * 4096;
  #pragma unroll
  for (int j = 0; j < 8; ++j){
    int oidx = j * 512 + tid;                  // px*64 + o, coalesced
    float v = bias;
    #pragma unroll
    for (int kvv = 0; kvv < 8; ++kvv) v += red[kvv * 4096 + oidx];
    outp[oidx] = v;
  }
}

extern "C" void kernel_launch(void* const* d_in, const int* in_sizes, int n_in,
                              void* d_out, int out_size, void* d_ws, size_t ws_size,
                              hipStream_t stream){
  const float* x      = (const float*)d_in[0];
  const float* W1     = (const float*)d_in[1];
  const float* W2     = (const float*)d_in[2];
  const float* bias_w = (const float*)d_in[3];
  float* out = (float*)d_out;
  uint4* Bpack = (uint4*)d_ws;                 // 448 KB

  volt_pack<<<112, 256, 0, stream>>>(W1, W2, Bpack);
  volt_main<<<256, 512, 0, stream>>>(x, (const uint4*)d_ws, bias_w, out);
}